// Round 2
// baseline (631.639 us; speedup 1.0000x reference)
//
#include <hip/hip_runtime.h>
#include <hip/hip_bf16.h>

#define S_ 256
#define DIM_ 1024
#define SOFTCAP_ 50.0f
#define EPS_ 1e-6f

typedef __attribute__((ext_vector_type(8))) short bf16x8;
typedef __attribute__((ext_vector_type(4))) float f32x4;

__device__ __forceinline__ unsigned short f2bf(float f) {
    unsigned u = __float_as_uint(f);
    u += 0x7FFFu + ((u >> 16) & 1u);
    return (unsigned short)(u >> 16);
}

// ---------------- Wkv -> bf16 fragment-layout swizzle ----------------
// layout: [kb(32)][nb(32)][lane(64)][j(8)]  value = W'[kb*32+(l>>4)*8+j][nb*16+(l&15)]
// n<256 -> Wk col n ; n>=256 -> Wv col n-256
__global__ void wkv_swizzle(const float* __restrict__ Wk, const float* __restrict__ Wv,
                            unsigned short* __restrict__ wkv) {
    int tid = blockIdx.x * 256 + threadIdx.x;   // 0..65535
    int l = tid & 63;
    int nb = (tid >> 6) & 31;
    int kb = tid >> 11;
    int n = nb * 16 + (l & 15);
    int kbase = kb * 32 + ((l >> 4) << 3);
    const float* src = (n < 256) ? (Wk + n) : (Wv + (n - 256));
    unsigned short r[8];
#pragma unroll
    for (int j = 0; j < 8; ++j) r[j] = f2bf(src[(size_t)(kbase + j) * 256]);
    uint4 o;
    o.x = (unsigned)r[0] | ((unsigned)r[1] << 16);
    o.y = (unsigned)r[2] | ((unsigned)r[3] << 16);
    o.z = (unsigned)r[4] | ((unsigned)r[5] << 16);
    o.w = (unsigned)r[6] | ((unsigned)r[7] << 16);
    *(uint4*)(wkv + (size_t)tid * 8) = o;
}

// ---------------- Q projection + RMSNorm ----------------
// grid (16,64): 64 cols x 8 rows per block. One head (64 cols) == one wave width.
__global__ __launch_bounds__(256) void qproj_kernel(
    const float* __restrict__ agent, const float* __restrict__ Wq,
    const float* __restrict__ q_gamma, float* __restrict__ ws_q)
{
    __shared__ float srows[8][1024];
    int cg = blockIdx.x, rg = blockIdx.y;
    int t = threadIdx.x;
#pragma unroll
    for (int j = 0; j < 8; ++j) {
        int f = j * 256 + t;          // float4 index 0..2047
        int row = f >> 8, c4 = f & 255;
        *(float4*)&srows[row][c4 * 4] =
            *(const float4*)(agent + (size_t)(rg * 8 + row) * 1024 + c4 * 4);
    }
    __syncthreads();
    int c = cg * 64 + (t & 63);
    int rq = t >> 6;                  // 2 rows per thread: rq*2, rq*2+1
    float acc0 = 0.f, acc1 = 0.f;
    for (int k = 0; k < 1024; k += 4) {
        float w0 = Wq[(size_t)(k + 0) * 1024 + c];
        float w1 = Wq[(size_t)(k + 1) * 1024 + c];
        float w2 = Wq[(size_t)(k + 2) * 1024 + c];
        float w3 = Wq[(size_t)(k + 3) * 1024 + c];
        float4 a0 = *(const float4*)&srows[rq * 2][k];
        float4 a1 = *(const float4*)&srows[rq * 2 + 1][k];
        acc0 += a0.x * w0 + a0.y * w1 + a0.z * w2 + a0.w * w3;
        acc1 += a1.x * w0 + a1.y * w1 + a1.z * w2 + a1.w * w3;
    }
    float g = q_gamma[t & 63];
    float ss0 = acc0 * acc0, ss1 = acc1 * acc1;
#pragma unroll
    for (int d = 1; d < 64; d <<= 1) { ss0 += __shfl_xor(ss0, d); ss1 += __shfl_xor(ss1, d); }
    float rs0 = rsqrtf(ss0 * (1.0f / 64.0f) + EPS_);
    float rs1 = rsqrtf(ss1 * (1.0f / 64.0f) + EPS_);
    ws_q[(size_t)(rg * 8 + rq * 2 + 0) * 1024 + c] = acc0 * rs0 * g;
    ws_q[(size_t)(rg * 8 + rq * 2 + 1) * 1024 + c] = acc1 * rs1 * g;
}

// ---------------- Fused KV projection + attention ----------------
// 1 block per (b,t). 4 waves; wave w = kv head w. Double-buffered LDS slices
// (64 rows x 128 cols) with register prefetch: loads for slice t+1 issued at
// tail of iter t-1, in flight across barrier+compute of iter t.
__global__ __launch_bounds__(256, 2) void kv_attn_kernel(
    const float* __restrict__ z, const unsigned short* __restrict__ wkv,
    const float* __restrict__ ws_q, const float* __restrict__ k_gamma,
    float* __restrict__ ws_att)
{
    __shared__ __align__(16) unsigned short lds[2][64 * 128];   // 2 x 16KB, XOR-swizzled bf16
    const int bt = blockIdx.x;
    const int tid = threadIdx.x;
    const int w = tid >> 6;
    const int l = tid & 63;
    const int l15 = l & 15;
    const int lg = l >> 4;
    const int tr = tid >> 5;        // staging row-within-8 (0..7)
    const int c4 = tid & 31;        // staging float4-col (0..31)
    const float* zb = z + (size_t)bt * (S_ * DIM_);

    float qn[4][4], kgm[4];
#pragma unroll
    for (int g = 0; g < 4; ++g)
#pragma unroll
        for (int ni = 0; ni < 4; ++ni)
            qn[g][ni] = ws_q[(size_t)bt * 1024 + (4 * w + g) * 64 + ni * 16 + l15];
#pragma unroll
    for (int ni = 0; ni < 4; ++ni) kgm[ni] = k_gamma[ni * 16 + l15];

    float out_acc[4][4] = {};
    float denom[4] = {};
    f32x4 acc[4][8];
    float4 pf[8];

    // ---- prologue: stage slice 0 into lds[0]; issue loads for slice 1 ----
#pragma unroll
    for (int j = 0; j < 8; ++j)
        pf[j] = *(const float4*)(zb + (size_t)(j * 8 + tr) * 1024 + c4 * 4);
#pragma unroll
    for (int j = 0; j < 8; ++j) {
        unsigned lo = (unsigned)f2bf(pf[j].x) | ((unsigned)f2bf(pf[j].y) << 16);
        unsigned hi = (unsigned)f2bf(pf[j].z) | ((unsigned)f2bf(pf[j].w) << 16);
        int byteoff = (((j * 8 + tr) * 256) + c4 * 8) ^ (tr << 4);
        *(uint2*)((char*)lds[0] + byteoff) = (uint2){lo, hi};
    }
#pragma unroll
    for (int j = 0; j < 8; ++j)
        pf[j] = *(const float4*)(zb + (size_t)(j * 8 + tr) * 1024 + 128 + c4 * 4);

    for (int t = 0; t < 32; ++t) {          // stage index: chunk c = t>>3, k-slice sl = t&7
        if ((t & 7) == 0) {
#pragma unroll
            for (int mi = 0; mi < 4; ++mi)
#pragma unroll
                for (int ni = 0; ni < 8; ++ni) acc[mi][ni] = (f32x4){0.f, 0.f, 0.f, 0.f};
        }
        __syncthreads();
        const int cur = t & 1;
        // ---- compute: 4 k-steps x 32 MFMA from lds[cur] ----
#pragma unroll
        for (int ks = 0; ks < 4; ++ks) {
            const int kb = (t & 7) * 4 + ks;
            bf16x8 a[4], b[8];
#pragma unroll
            for (int mi = 0; mi < 4; ++mi) {
                int row = mi * 16 + l15;
                int byteoff = ((row * 256) + ks * 64 + lg * 16) ^ ((l15 & 7) << 4);
                a[mi] = *(const bf16x8*)((const char*)lds[cur] + byteoff);
            }
#pragma unroll
            for (int ni = 0; ni < 8; ++ni) {
                int nb = (ni < 4) ? (w * 4 + ni) : (16 + w * 4 + ni - 4);
                b[ni] = *(const bf16x8*)(wkv + ((size_t)(kb * 32 + nb) * 64 + l) * 8);
            }
#pragma unroll
            for (int mi = 0; mi < 4; ++mi)
#pragma unroll
                for (int ni = 0; ni < 8; ++ni)
                    acc[mi][ni] = __builtin_amdgcn_mfma_f32_16x16x32_bf16(
                        a[mi], b[ni], acc[mi][ni], 0, 0, 0);
        }
        // ---- write prefetched slice t+1 into other buffer; issue loads for t+2 ----
        if (t < 31) {
#pragma unroll
            for (int j = 0; j < 8; ++j) {
                unsigned lo = (unsigned)f2bf(pf[j].x) | ((unsigned)f2bf(pf[j].y) << 16);
                unsigned hi = (unsigned)f2bf(pf[j].z) | ((unsigned)f2bf(pf[j].w) << 16);
                int byteoff = (((j * 8 + tr) * 256) + c4 * 8) ^ (tr << 4);
                *(uint2*)((char*)lds[(t + 1) & 1] + byteoff) = (uint2){lo, hi};
            }
            if (t < 30) {
                const int nt = t + 2;
#pragma unroll
                for (int j = 0; j < 8; ++j)
                    pf[j] = *(const float4*)(zb + (size_t)((nt >> 3) * 64 + j * 8 + tr) * 1024
                                                + (nt & 7) * 128 + c4 * 4);
            }
        }
        // ---- per-chunk attention epilogue (in-register) ----
        if ((t & 7) == 7) {
#pragma unroll
            for (int mi = 0; mi < 4; ++mi) {
#pragma unroll
                for (int r = 0; r < 4; ++r) {
                    float k0 = acc[mi][0][r], k1 = acc[mi][1][r], k2 = acc[mi][2][r], k3 = acc[mi][3][r];
                    float ss = k0 * k0 + k1 * k1 + k2 * k2 + k3 * k3;
                    ss += __shfl_xor(ss, 1); ss += __shfl_xor(ss, 2);
                    ss += __shfl_xor(ss, 4); ss += __shfl_xor(ss, 8);
                    float rs = rsqrtf(ss * (1.0f / 64.0f) + EPS_);
                    k0 *= rs * kgm[0]; k1 *= rs * kgm[1]; k2 *= rs * kgm[2]; k3 *= rs * kgm[3];
#pragma unroll
                    for (int g = 0; g < 4; ++g) {
                        float sp = qn[g][0] * k0 + qn[g][1] * k1 + qn[g][2] * k2 + qn[g][3] * k3;
                        sp += __shfl_xor(sp, 1); sp += __shfl_xor(sp, 2);
                        sp += __shfl_xor(sp, 4); sp += __shfl_xor(sp, 8);
                        float sc = sp * 0.125f;                    // * hd^-0.5
                        float e2 = __expf(sc * (2.0f / SOFTCAP_)); // e^(2x), x=sc/50
                        float th = 1.0f - 2.0f / (e2 + 1.0f);      // tanh(x)
                        float p = __expf(SOFTCAP_ * th);           // |capped|<=50, fp32-safe
                        denom[g] += p;
                        out_acc[g][0] += p * acc[mi][4][r];
                        out_acc[g][1] += p * acc[mi][5][r];
                        out_acc[g][2] += p * acc[mi][6][r];
                        out_acc[g][3] += p * acc[mi][7][r];
                    }
                }
            }
        }
    }
    // cross-lane-group reduce, normalize, write
#pragma unroll
    for (int g = 0; g < 4; ++g) {
        float d = denom[g];
        d += __shfl_xor(d, 16); d += __shfl_xor(d, 32);
        float inv = 1.0f / d;
#pragma unroll
        for (int nv = 0; nv < 4; ++nv) {
            float o = out_acc[g][nv];
            o += __shfl_xor(o, 16); o += __shfl_xor(o, 32);
            if (lg == 0)
                ws_att[(size_t)bt * 1024 + (4 * w + g) * 64 + nv * 16 + l15] = o * inv;
        }
    }
}

// ---------------- Output projection ----------------
__global__ __launch_bounds__(256) void oproj_kernel(
    const float* __restrict__ att, const float* __restrict__ Wo,
    float* __restrict__ out)
{
    __shared__ float srows[8][1024];
    int cg = blockIdx.x, rg = blockIdx.y;
    int t = threadIdx.x;
#pragma unroll
    for (int j = 0; j < 8; ++j) {
        int f = j * 256 + t;
        int row = f >> 8, c4 = f & 255;
        *(float4*)&srows[row][c4 * 4] =
            *(const float4*)(att + (size_t)(rg * 8 + row) * 1024 + c4 * 4);
    }
    __syncthreads();
    int c = cg * 64 + (t & 63);
    int rq = t >> 6;
    float acc0 = 0.f, acc1 = 0.f;
    for (int k = 0; k < 1024; k += 4) {
        float w0 = Wo[(size_t)(k + 0) * 1024 + c];
        float w1 = Wo[(size_t)(k + 1) * 1024 + c];
        float w2 = Wo[(size_t)(k + 2) * 1024 + c];
        float w3 = Wo[(size_t)(k + 3) * 1024 + c];
        float4 a0 = *(const float4*)&srows[rq * 2][k];
        float4 a1 = *(const float4*)&srows[rq * 2 + 1][k];
        acc0 += a0.x * w0 + a0.y * w1 + a0.z * w2 + a0.w * w3;
        acc1 += a1.x * w0 + a1.y * w1 + a1.z * w2 + a1.w * w3;
    }
    out[(size_t)(rg * 8 + rq * 2 + 0) * 1024 + c] = acc0;
    out[(size_t)(rg * 8 + rq * 2 + 1) * 1024 + c] = acc1;
}

extern "C" void kernel_launch(void* const* d_in, const int* in_sizes, int n_in,
                              void* d_out, int out_size, void* d_ws, size_t ws_size,
                              hipStream_t stream) {
    const float* agent = (const float*)d_in[0];
    const float* z     = (const float*)d_in[1];
    const float* Wq    = (const float*)d_in[2];
    const float* Wk    = (const float*)d_in[3];
    const float* Wv    = (const float*)d_in[4];
    const float* Wo    = (const float*)d_in[5];
    const float* qg    = (const float*)d_in[6];
    const float* kg    = (const float*)d_in[7];
    float* out = (float*)d_out;

    char* ws = (char*)d_ws;
    float* ws_q   = (float*)ws;                          // 2 MB
    float* ws_att = (float*)(ws + (2u << 20));           // 2 MB
    unsigned short* ws_wkv = (unsigned short*)(ws + (4u << 20)); // 1 MB

    hipLaunchKernelGGL(wkv_swizzle, dim3(256), dim3(256), 0, stream, Wk, Wv, ws_wkv);
    hipLaunchKernelGGL(qproj_kernel, dim3(16, 64), dim3(256), 0, stream, agent, Wq, qg, ws_q);
    hipLaunchKernelGGL(kv_attn_kernel, dim3(512), dim3(256), 0, stream, z, ws_wkv, ws_q, kg, ws_att);
    hipLaunchKernelGGL(oproj_kernel, dim3(16, 64), dim3(256), 0, stream, ws_att, Wo, out);
}

// Round 6
// 571.251 us; speedup vs baseline: 1.1057x; 1.1057x over previous
//
// Round 6: resubmit of round-5 kernel — round 5 failed with "No space left on
// device" during compilation (container disk full), the kernel never ran.
#include <hip/hip_runtime.h>
#include <hip/hip_bf16.h>

#define SOFTCAP_ 50.0f
#define EPS_ 1e-6f

typedef __attribute__((ext_vector_type(8))) short bf16x8;
typedef __attribute__((ext_vector_type(4))) float f32x4;

__device__ __forceinline__ unsigned short f2bf(float f) {
    unsigned u = __float_as_uint(f);
    u += 0x7FFFu + ((u >> 16) & 1u);
    return (unsigned short)(u >> 16);
}

// ---------------- Wkv -> bf16 fragment-layout swizzle ----------------
// layout: [kb(32)][nb(32)][lane(64)][j(8)]  value = W'[kb*32+(l>>4)*8+j][nb*16+(l&15)]
// n<256 -> Wk col n ; n>=256 -> Wv col n-256
__global__ void wkv_swizzle(const float* __restrict__ Wk, const float* __restrict__ Wv,
                            unsigned short* __restrict__ wkv) {
    int tid = blockIdx.x * 256 + threadIdx.x;   // 0..65535
    int l = tid & 63;
    int nb = (tid >> 6) & 31;
    int kb = tid >> 11;
    int n = nb * 16 + (l & 15);
    int kbase = kb * 32 + ((l >> 4) << 3);
    const float* src = (n < 256) ? (Wk + n) : (Wv + (n - 256));
    unsigned short r[8];
#pragma unroll
    for (int j = 0; j < 8; ++j) r[j] = f2bf(src[(size_t)(kbase + j) * 256]);
    uint4 o;
    o.x = (unsigned)r[0] | ((unsigned)r[1] << 16);
    o.y = (unsigned)r[2] | ((unsigned)r[3] << 16);
    o.z = (unsigned)r[4] | ((unsigned)r[5] << 16);
    o.w = (unsigned)r[6] | ((unsigned)r[7] << 16);
    *(uint4*)(wkv + (size_t)tid * 8) = o;
}

// ---------------- Q projection + RMSNorm ----------------
__global__ __launch_bounds__(256) void qproj_kernel(
    const float* __restrict__ agent, const float* __restrict__ Wq,
    const float* __restrict__ q_gamma, float* __restrict__ ws_q)
{
    __shared__ float srows[8][1024];
    int cg = blockIdx.x, rg = blockIdx.y;
    int t = threadIdx.x;
#pragma unroll
    for (int j = 0; j < 8; ++j) {
        int f = j * 256 + t;          // float4 index 0..2047
        int row = f >> 8, c4 = f & 255;
        *(float4*)&srows[row][c4 * 4] =
            *(const float4*)(agent + (size_t)(rg * 8 + row) * 1024 + c4 * 4);
    }
    __syncthreads();
    int c = cg * 64 + (t & 63);
    int rq = t >> 6;                  // 2 rows per thread
    float acc0 = 0.f, acc1 = 0.f;
    for (int k = 0; k < 1024; k += 4) {
        float w0 = Wq[(size_t)(k + 0) * 1024 + c];
        float w1 = Wq[(size_t)(k + 1) * 1024 + c];
        float w2 = Wq[(size_t)(k + 2) * 1024 + c];
        float w3 = Wq[(size_t)(k + 3) * 1024 + c];
        float4 a0 = *(const float4*)&srows[rq * 2][k];
        float4 a1 = *(const float4*)&srows[rq * 2 + 1][k];
        acc0 += a0.x * w0 + a0.y * w1 + a0.z * w2 + a0.w * w3;
        acc1 += a1.x * w0 + a1.y * w1 + a1.z * w2 + a1.w * w3;
    }
    float g = q_gamma[t & 63];
    float ss0 = acc0 * acc0, ss1 = acc1 * acc1;
#pragma unroll
    for (int d = 1; d < 64; d <<= 1) { ss0 += __shfl_xor(ss0, d); ss1 += __shfl_xor(ss1, d); }
    float rs0 = rsqrtf(ss0 * (1.0f / 64.0f) + EPS_);
    float rs1 = rsqrtf(ss1 * (1.0f / 64.0f) + EPS_);
    ws_q[(size_t)(rg * 8 + rq * 2 + 0) * 1024 + c] = acc0 * rs0 * g;
    ws_q[(size_t)(rg * 8 + rq * 2 + 1) * 1024 + c] = acc1 * rs1 * g;
}

// ---------------- Fused KV projection + attention ----------------
// grid 512 = bt, 512 threads = 8 waves. Wave w: head = w&3, row-half = w>>2.
// Each wave computes K-scores AND V rows for its 32 s-rows (acc[2][8], 64 regs);
// softcap => plain sum softmax, so everything stays in-wave. One final barrier
// combines the two half-partials per head through LDS. No mid-loop role split.
__global__ __launch_bounds__(512, 4) void kv_attn_kernel(
    const float* __restrict__ z, const unsigned short* __restrict__ wkv,
    const float* __restrict__ ws_q, const float* __restrict__ k_gamma,
    float* __restrict__ ws_att)
{
    __shared__ __align__(16) unsigned short zlds[64 * 256];   // 32 KB, XOR-swizzled bf16
    __shared__ float compub[4][4][5][16];                     // 5 KB: head,g,{4 ni + den},l15
    const int bt = blockIdx.x;
    const int tid = threadIdx.x;
    const int w = tid >> 6;
    const int head = w & 3;
    const int half = w >> 2;
    const int l = tid & 63, l15 = l & 15, lg = l >> 4;

    float out_acc[4][4] = {};
    float denom[4] = {};

    for (int c = 0; c < 4; ++c) {          // 4 chunks of 64 s-rows
        f32x4 acc[2][8];
#pragma unroll
        for (int mi = 0; mi < 2; ++mi)
#pragma unroll
            for (int ni = 0; ni < 8; ++ni) acc[mi][ni] = (f32x4){0.f, 0.f, 0.f, 0.f};

        for (int sl = 0; sl < 4; ++sl) {   // k-slices of 256
            __syncthreads();               // prior reads of zlds done
#pragma unroll
            for (int j = 0; j < 8; ++j) {  // stage 64x256 fp32 -> bf16 (512 threads)
                int f = j * 512 + tid;     // float4 idx 0..4095
                int row = f >> 6, c4 = f & 63;
                float4 v4 = *(const float4*)(z + (size_t)(bt * 256 + c * 64 + row) * 1024
                                               + sl * 256 + c4 * 4);
                unsigned lo = (unsigned)f2bf(v4.x) | ((unsigned)f2bf(v4.y) << 16);
                unsigned hi = (unsigned)f2bf(v4.z) | ((unsigned)f2bf(v4.w) << 16);
                int byteoff = ((row * 512) + c4 * 8) ^ ((row & 7) << 4);
                *(uint2*)((char*)zlds + byteoff) = (uint2){lo, hi};
            }
            __syncthreads();               // stage visible
#pragma unroll
            for (int ksl = 0; ksl < 8; ++ksl) {
                const int kb = sl * 8 + ksl;
                int boff0 = (((half * 32 + l15) * 512) + ksl * 64 + lg * 16) ^ ((l15 & 7) << 4);
                bf16x8 a0 = *(const bf16x8*)((const char*)zlds + boff0);
                bf16x8 a1 = *(const bf16x8*)((const char*)zlds + boff0 + 8192); // row+16
                bf16x8 b[8];
#pragma unroll
                for (int ni = 0; ni < 8; ++ni) {
                    int nb = (ni < 4) ? (head * 4 + ni) : (16 + head * 4 + ni - 4);
                    b[ni] = *(const bf16x8*)(wkv + ((size_t)(kb * 32 + nb) * 64 + l) * 8);
                }
#pragma unroll
                for (int ni = 0; ni < 8; ++ni) {
                    acc[0][ni] = __builtin_amdgcn_mfma_f32_16x16x32_bf16(a0, b[ni], acc[0][ni], 0, 0, 0);
                    acc[1][ni] = __builtin_amdgcn_mfma_f32_16x16x32_bf16(a1, b[ni], acc[1][ni], 0, 0, 0);
                }
            }
        }
        // ---- in-wave attention epilogue for this chunk's 32 rows ----
#pragma unroll
        for (int mi = 0; mi < 2; ++mi) {
#pragma unroll
            for (int r = 0; r < 4; ++r) {
                float k0 = acc[mi][0][r], k1 = acc[mi][1][r], k2 = acc[mi][2][r], k3 = acc[mi][3][r];
                float ss = k0 * k0 + k1 * k1 + k2 * k2 + k3 * k3;
                ss += __shfl_xor(ss, 1); ss += __shfl_xor(ss, 2);
                ss += __shfl_xor(ss, 4); ss += __shfl_xor(ss, 8);
                float rs = rsqrtf(ss * (1.0f / 64.0f) + EPS_);
                k0 *= rs * k_gamma[l15];
                k1 *= rs * k_gamma[16 + l15];
                k2 *= rs * k_gamma[32 + l15];
                k3 *= rs * k_gamma[48 + l15];
#pragma unroll
                for (int g = 0; g < 4; ++g) {
                    const float* qb = ws_q + (size_t)bt * 1024 + (head * 4 + g) * 64 + l15;
                    float sp = qb[0] * k0 + qb[16] * k1 + qb[32] * k2 + qb[48] * k3;
                    sp += __shfl_xor(sp, 1); sp += __shfl_xor(sp, 2);
                    sp += __shfl_xor(sp, 4); sp += __shfl_xor(sp, 8);
                    float scv = sp * 0.125f;                    // * hd^-0.5
                    float e2 = __expf(scv * (2.0f / SOFTCAP_));
                    float th = 1.0f - 2.0f / (e2 + 1.0f);       // tanh
                    float p = __expf(SOFTCAP_ * th);            // |capped|<=50, fp32-safe
                    denom[g] += p;
                    out_acc[g][0] += p * acc[mi][4][r];
                    out_acc[g][1] += p * acc[mi][5][r];
                    out_acc[g][2] += p * acc[mi][6][r];
                    out_acc[g][3] += p * acc[mi][7][r];
                }
            }
        }
    }
    // ---- cross-half combine: half=1 publishes, half=0 merges + writes ----
    if (half == 1) {
#pragma unroll
        for (int g = 0; g < 4; ++g) {
            float d = denom[g];
            d += __shfl_xor(d, 16); d += __shfl_xor(d, 32);
#pragma unroll
            for (int ni = 0; ni < 4; ++ni) {
                float o = out_acc[g][ni];
                o += __shfl_xor(o, 16); o += __shfl_xor(o, 32);
                if (lg == 0) compub[head][g][ni][l15] = o;
            }
            if (lg == 0) compub[head][g][4][l15] = d;
        }
    }
    __syncthreads();
    if (half == 0) {
#pragma unroll
        for (int g = 0; g < 4; ++g) {
            float d = denom[g];
            d += __shfl_xor(d, 16); d += __shfl_xor(d, 32);
            d += compub[head][g][4][l15];
            float inv = 1.0f / d;
#pragma unroll
            for (int ni = 0; ni < 4; ++ni) {
                float o = out_acc[g][ni];
                o += __shfl_xor(o, 16); o += __shfl_xor(o, 32);
                o += compub[head][g][ni][l15];
                if (lg == 0)
                    ws_att[(size_t)bt * 1024 + (head * 4 + g) * 64 + ni * 16 + l15] = o * inv;
            }
        }
    }
}

// ---------------- Output projection ----------------
__global__ __launch_bounds__(256) void oproj_kernel(
    const float* __restrict__ att, const float* __restrict__ Wo,
    float* __restrict__ out)
{
    __shared__ float srows[8][1024];
    int cg = blockIdx.x, rg = blockIdx.y;
    int t = threadIdx.x;
#pragma unroll
    for (int j = 0; j < 8; ++j) {
        int f = j * 256 + t;
        int row = f >> 8, c4 = f & 255;
        *(float4*)&srows[row][c4 * 4] =
            *(const float4*)(att + (size_t)(rg * 8 + row) * 1024 + c4 * 4);
    }
    __syncthreads();
    int c = cg * 64 + (t & 63);
    int rq = t >> 6;
    float acc0 = 0.f, acc1 = 0.f;
    for (int k = 0; k < 1024; k += 4) {
        float w0 = Wo[(size_t)(k + 0) * 1024 + c];
        float w1 = Wo[(size_t)(k + 1) * 1024 + c];
        float w2 = Wo[(size_t)(k + 2) * 1024 + c];
        float w3 = Wo[(size_t)(k + 3) * 1024 + c];
        float4 a0 = *(const float4*)&srows[rq * 2][k];
        float4 a1 = *(const float4*)&srows[rq * 2 + 1][k];
        acc0 += a0.x * w0 + a0.y * w1 + a0.z * w2 + a0.w * w3;
        acc1 += a1.x * w0 + a1.y * w1 + a1.z * w2 + a1.w * w3;
    }
    out[(size_t)(rg * 8 + rq * 2 + 0) * 1024 + c] = acc0;
    out[(size_t)(rg * 8 + rq * 2 + 1) * 1024 + c] = acc1;
}

extern "C" void kernel_launch(void* const* d_in, const int* in_sizes, int n_in,
                              void* d_out, int out_size, void* d_ws, size_t ws_size,
                              hipStream_t stream) {
    const float* agent = (const float*)d_in[0];
    const float* z     = (const float*)d_in[1];
    const float* Wq    = (const float*)d_in[2];
    const float* Wk    = (const float*)d_in[3];
    const float* Wv    = (const float*)d_in[4];
    const float* Wo    = (const float*)d_in[5];
    const float* qg    = (const float*)d_in[6];
    const float* kg    = (const float*)d_in[7];
    float* out = (float*)d_out;

    char* ws = (char*)d_ws;
    float* ws_q   = (float*)ws;                          // 2 MB
    float* ws_att = (float*)(ws + (2u << 20));           // 2 MB
    unsigned short* ws_wkv = (unsigned short*)(ws + (4u << 20)); // 1 MB  (total 5 MB, proven)

    hipLaunchKernelGGL(wkv_swizzle, dim3(256), dim3(256), 0, stream, Wk, Wv, ws_wkv);
    hipLaunchKernelGGL(qproj_kernel, dim3(16, 64), dim3(256), 0, stream, agent, Wq, qg, ws_q);
    hipLaunchKernelGGL(kv_attn_kernel, dim3(512), dim3(512), 0, stream, z, ws_wkv, ws_q, kg, ws_att);
    hipLaunchKernelGGL(oproj_kernel, dim3(16, 64), dim3(256), 0, stream, ws_att, Wo, out);
}

// Round 7
// 435.133 us; speedup vs baseline: 1.4516x; 1.3128x over previous
//
// Round 7: K/V wave-specialized kv_attn (round-4 structure, resubmitted on the
// now-healthy container) + qn preload. Rationale: only decomposition found where
// every wave fits <=128 unified regs (no scratch spill) at 4 waves/SIMD.
#include <hip/hip_runtime.h>
#include <hip/hip_bf16.h>

#define SOFTCAP_ 50.0f
#define EPS_ 1e-6f

typedef __attribute__((ext_vector_type(8))) short bf16x8;
typedef __attribute__((ext_vector_type(4))) float f32x4;

__device__ __forceinline__ unsigned short f2bf(float f) {
    unsigned u = __float_as_uint(f);
    u += 0x7FFFu + ((u >> 16) & 1u);
    return (unsigned short)(u >> 16);
}

// ---------------- Wkv -> bf16 fragment-layout swizzle ----------------
// layout: [kb(32)][nb(32)][lane(64)][j(8)]  value = W'[kb*32+(l>>4)*8+j][nb*16+(l&15)]
// n<256 -> Wk col n ; n>=256 -> Wv col n-256
__global__ void wkv_swizzle(const float* __restrict__ Wk, const float* __restrict__ Wv,
                            unsigned short* __restrict__ wkv) {
    int tid = blockIdx.x * 256 + threadIdx.x;   // 0..65535
    int l = tid & 63;
    int nb = (tid >> 6) & 31;
    int kb = tid >> 11;
    int n = nb * 16 + (l & 15);
    int kbase = kb * 32 + ((l >> 4) << 3);
    const float* src = (n < 256) ? (Wk + n) : (Wv + (n - 256));
    unsigned short r[8];
#pragma unroll
    for (int j = 0; j < 8; ++j) r[j] = f2bf(src[(size_t)(kbase + j) * 256]);
    uint4 o;
    o.x = (unsigned)r[0] | ((unsigned)r[1] << 16);
    o.y = (unsigned)r[2] | ((unsigned)r[3] << 16);
    o.z = (unsigned)r[4] | ((unsigned)r[5] << 16);
    o.w = (unsigned)r[6] | ((unsigned)r[7] << 16);
    *(uint4*)(wkv + (size_t)tid * 8) = o;
}

// ---------------- Q projection + RMSNorm ----------------
__global__ __launch_bounds__(256) void qproj_kernel(
    const float* __restrict__ agent, const float* __restrict__ Wq,
    const float* __restrict__ q_gamma, float* __restrict__ ws_q)
{
    __shared__ float srows[8][1024];
    int cg = blockIdx.x, rg = blockIdx.y;
    int t = threadIdx.x;
#pragma unroll
    for (int j = 0; j < 8; ++j) {
        int f = j * 256 + t;          // float4 index 0..2047
        int row = f >> 8, c4 = f & 255;
        *(float4*)&srows[row][c4 * 4] =
            *(const float4*)(agent + (size_t)(rg * 8 + row) * 1024 + c4 * 4);
    }
    __syncthreads();
    int c = cg * 64 + (t & 63);
    int rq = t >> 6;                  // 2 rows per thread
    float acc0 = 0.f, acc1 = 0.f;
    for (int k = 0; k < 1024; k += 4) {
        float w0 = Wq[(size_t)(k + 0) * 1024 + c];
        float w1 = Wq[(size_t)(k + 1) * 1024 + c];
        float w2 = Wq[(size_t)(k + 2) * 1024 + c];
        float w3 = Wq[(size_t)(k + 3) * 1024 + c];
        float4 a0 = *(const float4*)&srows[rq * 2][k];
        float4 a1 = *(const float4*)&srows[rq * 2 + 1][k];
        acc0 += a0.x * w0 + a0.y * w1 + a0.z * w2 + a0.w * w3;
        acc1 += a1.x * w0 + a1.y * w1 + a1.z * w2 + a1.w * w3;
    }
    float g = q_gamma[t & 63];
    float ss0 = acc0 * acc0, ss1 = acc1 * acc1;
#pragma unroll
    for (int d = 1; d < 64; d <<= 1) { ss0 += __shfl_xor(ss0, d); ss1 += __shfl_xor(ss1, d); }
    float rs0 = rsqrtf(ss0 * (1.0f / 64.0f) + EPS_);
    float rs1 = rsqrtf(ss1 * (1.0f / 64.0f) + EPS_);
    ws_q[(size_t)(rg * 8 + rq * 2 + 0) * 1024 + c] = acc0 * rs0 * g;
    ws_q[(size_t)(rg * 8 + rq * 2 + 1) * 1024 + c] = acc1 * rs1 * g;
}

// ---------------- Fused KV projection + attention (K/V wave-specialized) ----------------
// grid 512 = bt, 512 threads = 8 waves. w<4: K-wave for kv-head w; w>=4: V-wave.
// 8 sub-chunks of 32 s-rows; acc[2][4] (32 regs) per wave -> no spills at 128-reg cap.
// K-waves compute RMSNorm+scores+softcap+exp, hand p to V-waves via p_lds (barrier);
// V-waves accumulate PV. Denominators combined in-block at the end.
__global__ __launch_bounds__(512, 4) void kv_attn_kernel(
    const float* __restrict__ z, const unsigned short* __restrict__ wkv,
    const float* __restrict__ ws_q, const float* __restrict__ k_gamma,
    float* __restrict__ ws_att)
{
    __shared__ __align__(16) unsigned short zlds[32 * 256];   // 16 KB, XOR-swizzled bf16
    __shared__ float p_lds[16 * 32];                          // 2 KB
    __shared__ float den_lds[16];
    const int bt = blockIdx.x;
    const int tid = threadIdx.x;
    const int w = tid >> 6;                // 0..7
    const bool isK = (w < 4);
    const int kvh = w & 3;                 // kv head 0..3
    const int nbase = isK ? (kvh * 4) : (16 + kvh * 4);
    const int l = tid & 63, l15 = l & 15, lg = l >> 4;

    float qn[4][4], kgm[4];                // K-waves only (live in their path)
    if (isK) {
#pragma unroll
        for (int g = 0; g < 4; ++g)
#pragma unroll
            for (int ni = 0; ni < 4; ++ni)
                qn[g][ni] = ws_q[(size_t)bt * 1024 + (kvh * 4 + g) * 64 + ni * 16 + l15];
#pragma unroll
        for (int ni = 0; ni < 4; ++ni) kgm[ni] = k_gamma[ni * 16 + l15];
    }

    float out_acc[4][4] = {};   // V-waves
    float denom[4] = {};        // K-waves

    for (int sc = 0; sc < 8; ++sc) {       // 8 sub-chunks of 32 s-rows
        f32x4 acc[2][4];
#pragma unroll
        for (int mi = 0; mi < 2; ++mi)
#pragma unroll
            for (int ni = 0; ni < 4; ++ni) acc[mi][ni] = (f32x4){0.f, 0.f, 0.f, 0.f};

        for (int sl = 0; sl < 4; ++sl) {   // k-slices of 256
            __syncthreads();               // prior reads of zlds (and p_lds) done
#pragma unroll
            for (int j = 0; j < 4; ++j) {  // stage 32x256 fp32 -> bf16
                int f = j * 512 + tid;     // float4 idx 0..2047
                int row = f >> 6, c4 = f & 63;
                float4 v4 = *(const float4*)(z + (size_t)(bt * 256 + sc * 32 + row) * 1024
                                               + sl * 256 + c4 * 4);
                unsigned lo = (unsigned)f2bf(v4.x) | ((unsigned)f2bf(v4.y) << 16);
                unsigned hi = (unsigned)f2bf(v4.z) | ((unsigned)f2bf(v4.w) << 16);
                int byteoff = ((row * 512) + c4 * 8) ^ ((row & 7) << 4);
                *(uint2*)((char*)zlds + byteoff) = (uint2){lo, hi};
            }
            __syncthreads();               // stage visible
#pragma unroll
            for (int ksl = 0; ksl < 8; ++ksl) {
                const int kb = sl * 8 + ksl;
                int boff0 = ((l15 * 512) + ksl * 64 + lg * 16) ^ ((l15 & 7) << 4);
                bf16x8 a0 = *(const bf16x8*)((const char*)zlds + boff0);
                bf16x8 a1 = *(const bf16x8*)((const char*)zlds + boff0 + 8192); // row+16: same swizzle
                bf16x8 b[4];
#pragma unroll
                for (int ni = 0; ni < 4; ++ni)
                    b[ni] = *(const bf16x8*)(wkv + ((size_t)(kb * 32 + nbase + ni) * 64 + l) * 8);
#pragma unroll
                for (int ni = 0; ni < 4; ++ni) {
                    acc[0][ni] = __builtin_amdgcn_mfma_f32_16x16x32_bf16(a0, b[ni], acc[0][ni], 0, 0, 0);
                    acc[1][ni] = __builtin_amdgcn_mfma_f32_16x16x32_bf16(a1, b[ni], acc[1][ni], 0, 0, 0);
                }
            }
        }
        // ---- epilogue: K-waves make p; V-waves consume after barrier ----
        if (isK) {
#pragma unroll
            for (int mi = 0; mi < 2; ++mi) {
#pragma unroll
                for (int r = 0; r < 4; ++r) {
                    float k0 = acc[mi][0][r], k1 = acc[mi][1][r], k2 = acc[mi][2][r], k3 = acc[mi][3][r];
                    float ss = k0 * k0 + k1 * k1 + k2 * k2 + k3 * k3;
                    ss += __shfl_xor(ss, 1); ss += __shfl_xor(ss, 2);
                    ss += __shfl_xor(ss, 4); ss += __shfl_xor(ss, 8);
                    float rs = rsqrtf(ss * (1.0f / 64.0f) + EPS_);
                    k0 *= rs * kgm[0]; k1 *= rs * kgm[1]; k2 *= rs * kgm[2]; k3 *= rs * kgm[3];
#pragma unroll
                    for (int g = 0; g < 4; ++g) {
                        float sp = qn[g][0] * k0 + qn[g][1] * k1 + qn[g][2] * k2 + qn[g][3] * k3;
                        sp += __shfl_xor(sp, 1); sp += __shfl_xor(sp, 2);
                        sp += __shfl_xor(sp, 4); sp += __shfl_xor(sp, 8);
                        float scv = sp * 0.125f;                    // * hd^-0.5
                        float e2 = __expf(scv * (2.0f / SOFTCAP_));
                        float th = 1.0f - 2.0f / (e2 + 1.0f);       // tanh
                        float p = __expf(SOFTCAP_ * th);            // |capped|<=50, fp32-safe
                        denom[g] += p;
                        if (l15 == g)
                            p_lds[(kvh * 4 + g) * 32 + mi * 16 + lg * 4 + r] = p;
                    }
                }
            }
        }
        __syncthreads();                   // p visible to V-waves
        if (!isK) {
#pragma unroll
            for (int mi = 0; mi < 2; ++mi)
#pragma unroll
                for (int r = 0; r < 4; ++r) {
                    int row = mi * 16 + lg * 4 + r;
#pragma unroll
                    for (int g = 0; g < 4; ++g) {
                        float p = p_lds[(kvh * 4 + g) * 32 + row];
                        out_acc[g][0] += p * acc[mi][0][r];
                        out_acc[g][1] += p * acc[mi][1][r];
                        out_acc[g][2] += p * acc[mi][2][r];
                        out_acc[g][3] += p * acc[mi][3][r];
                    }
                }
        }
        // next sc's first stage-barrier orders V's p_lds reads before K's next writes
    }
    // ---- finalize: K-waves publish denominators; V-waves normalize + write ----
    if (isK) {
#pragma unroll
        for (int g = 0; g < 4; ++g) {
            float d = denom[g];
            d += __shfl_xor(d, 16); d += __shfl_xor(d, 32);
            if (l == g) den_lds[kvh * 4 + g] = d;
        }
    }
    __syncthreads();
    if (!isK) {
#pragma unroll
        for (int g = 0; g < 4; ++g) {
            float inv = 1.0f / den_lds[kvh * 4 + g];
#pragma unroll
            for (int ni = 0; ni < 4; ++ni) {
                float o = out_acc[g][ni];
                o += __shfl_xor(o, 16); o += __shfl_xor(o, 32);
                if (lg == 0)
                    ws_att[(size_t)bt * 1024 + (kvh * 4 + g) * 64 + ni * 16 + l15] = o * inv;
            }
        }
    }
}

// ---------------- Output projection ----------------
__global__ __launch_bounds__(256) void oproj_kernel(
    const float* __restrict__ att, const float* __restrict__ Wo,
    float* __restrict__ out)
{
    __shared__ float srows[8][1024];
    int cg = blockIdx.x, rg = blockIdx.y;
    int t = threadIdx.x;
#pragma unroll
    for (int j = 0; j < 8; ++j) {
        int f = j * 256 + t;
        int row = f >> 8, c4 = f & 255;
        *(float4*)&srows[row][c4 * 4] =
            *(const float4*)(att + (size_t)(rg * 8 + row) * 1024 + c4 * 4);
    }
    __syncthreads();
    int c = cg * 64 + (t & 63);
    int rq = t >> 6;
    float acc0 = 0.f, acc1 = 0.f;
    for (int k = 0; k < 1024; k += 4) {
        float w0 = Wo[(size_t)(k + 0) * 1024 + c];
        float w1 = Wo[(size_t)(k + 1) * 1024 + c];
        float w2 = Wo[(size_t)(k + 2) * 1024 + c];
        float w3 = Wo[(size_t)(k + 3) * 1024 + c];
        float4 a0 = *(const float4*)&srows[rq * 2][k];
        float4 a1 = *(const float4*)&srows[rq * 2 + 1][k];
        acc0 += a0.x * w0 + a0.y * w1 + a0.z * w2 + a0.w * w3;
        acc1 += a1.x * w0 + a1.y * w1 + a1.z * w2 + a1.w * w3;
    }
    out[(size_t)(rg * 8 + rq * 2 + 0) * 1024 + c] = acc0;
    out[(size_t)(rg * 8 + rq * 2 + 1) * 1024 + c] = acc1;
}

extern "C" void kernel_launch(void* const* d_in, const int* in_sizes, int n_in,
                              void* d_out, int out_size, void* d_ws, size_t ws_size,
                              hipStream_t stream) {
    const float* agent = (const float*)d_in[0];
    const float* z     = (const float*)d_in[1];
    const float* Wq    = (const float*)d_in[2];
    const float* Wk    = (const float*)d_in[3];
    const float* Wv    = (const float*)d_in[4];
    const float* Wo    = (const float*)d_in[5];
    const float* qg    = (const float*)d_in[6];
    const float* kg    = (const float*)d_in[7];
    float* out = (float*)d_out;

    char* ws = (char*)d_ws;
    float* ws_q   = (float*)ws;                          // 2 MB
    float* ws_att = (float*)(ws + (2u << 20));           // 2 MB
    unsigned short* ws_wkv = (unsigned short*)(ws + (4u << 20)); // 1 MB  (total 5 MB, proven)

    hipLaunchKernelGGL(wkv_swizzle, dim3(256), dim3(256), 0, stream, Wk, Wv, ws_wkv);
    hipLaunchKernelGGL(qproj_kernel, dim3(16, 64), dim3(256), 0, stream, agent, Wq, qg, ws_q);
    hipLaunchKernelGGL(kv_attn_kernel, dim3(512), dim3(512), 0, stream, z, ws_wkv, ws_q, kg, ws_att);
    hipLaunchKernelGGL(oproj_kernel, dim3(16, 64), dim3(256), 0, stream, ws_att, Wo, out);
}